// Round 11
// baseline (1709.065 us; speedup 1.0000x reference)
//
#include <hip/hip_runtime.h>
#include <hip/hip_bf16.h>
#include <cstdint>
#include <cstddef>

// Problem constants
#define NB   64
#define NS   8
#define DIM  2048
#define FF   4096
#define NE   8
#define TOK  512            // NB*NS
#define NPAIR 1024          // TOK*2

// GEMM tiling
#define BM   192            // 4 M-waves x 48 rows
#define BN   64             // N-cols per block (2 N-waves x 32)
#define BKE  32             // K per epoch

typedef __attribute__((ext_vector_type(4))) float f32x4;
typedef __attribute__((ext_vector_type(8))) short bf16x8;
typedef __attribute__((ext_vector_type(4))) short bf16x4;

#define MFMA16(a, b, c) __builtin_amdgcn_mfma_f32_16x16x32_bf16((a), (b), (c), 0, 0, 0)
#define SCHEDBAR __builtin_amdgcn_sched_barrier(0)
#define VMCNT8  asm volatile("s_waitcnt vmcnt(8)" ::: "memory")
#define VMCNT4  asm volatile("s_waitcnt vmcnt(4)" ::: "memory")
#define VMCNT0  asm volatile("s_waitcnt vmcnt(0)" ::: "memory")
#define LGKMBAR do { asm volatile("s_waitcnt lgkmcnt(0)" ::: "memory"); \
                     asm volatile("s_barrier" ::: "memory");            \
                     __builtin_amdgcn_sched_barrier(0); } while (0)
#define LGKMONLY do { asm volatile("s_waitcnt lgkmcnt(0)" ::: "memory"); \
                      __builtin_amdgcn_sched_barrier(0); } while (0)
// DCE guard (rule #17): keep a 16B value live without cost
#define SINKV(x) asm volatile("" :: "v"(*(const f32x4*)&(x)))

// round-half-up fp32 -> bf16
static __device__ __forceinline__ short f2bf(float f) {
    unsigned u = __builtin_bit_cast(unsigned, f);
    return (short)((u + 0x8000u) >> 16);
}

static __device__ __forceinline__ void async16(void* l, const void* g) {
    __builtin_amdgcn_global_load_lds(
        (const __attribute__((address_space(1))) void*)g,
        (__attribute__((address_space(3))) void*)l, 16, 0, 0);
}

// ---------------------------------------------------------------------------
// Kernel 1: gating + x -> bf16 preconvert.
// ---------------------------------------------------------------------------
__global__ void gate_topk(const float* __restrict__ x, const float* __restrict__ gw,
                          unsigned short* __restrict__ xbf,
                          int* __restrict__ tok_expert, float* __restrict__ tok_gatew) {
    int token = blockIdx.x;
    int lane  = threadIdx.x;
    const float* xr = x + (size_t)token * DIM;

    float acc[NE];
#pragma unroll
    for (int e = 0; e < NE; ++e) acc[e] = 0.f;

    for (int d0 = lane * 8; d0 < DIM; d0 += 64 * 8) {
        float4 xa = *(const float4*)(xr + d0);
        float4 xb = *(const float4*)(xr + d0 + 4);
        bf16x8 v;
        v[0] = f2bf(xa.x); v[1] = f2bf(xa.y); v[2] = f2bf(xa.z); v[3] = f2bf(xa.w);
        v[4] = f2bf(xb.x); v[5] = f2bf(xb.y); v[6] = f2bf(xb.z); v[7] = f2bf(xb.w);
        *(bf16x8*)(xbf + (size_t)token * DIM + d0) = v;
#pragma unroll
        for (int j = 0; j < 8; ++j) {
            float xv = (j < 4) ? ((const float*)&xa)[j] : ((const float*)&xb)[j - 4];
            const float4* g = (const float4*)(gw + (size_t)(d0 + j) * NE);
            float4 g0 = g[0], g1 = g[1];
            acc[0] += xv * g0.x; acc[1] += xv * g0.y;
            acc[2] += xv * g0.z; acc[3] += xv * g0.w;
            acc[4] += xv * g1.x; acc[5] += xv * g1.y;
            acc[6] += xv * g1.z; acc[7] += xv * g1.w;
        }
    }
#pragma unroll
    for (int off = 32; off >= 1; off >>= 1) {
#pragma unroll
        for (int e = 0; e < NE; ++e) acc[e] += __shfl_down(acc[e], off);
    }
    if (lane == 0) {
        float b1 = -1e30f, b2 = -1e30f; int i1 = 0, i2 = 0;
#pragma unroll
        for (int e = 0; e < NE; ++e) {
            float v = acc[e];
            if (v > b1) { b2 = b1; i2 = i1; b1 = v; i1 = e; }
            else if (v > b2) { b2 = v; i2 = e; }
        }
        float t = __expf(b2 - b1);
        tok_expert[token * 2 + 0] = i1;
        tok_expert[token * 2 + 1] = i2;
        tok_gatew[token * 2 + 0] = 1.f / (1.f + t);
        tok_gatew[token * 2 + 1] = t / (1.f + t);
    }
}

// ---------------------------------------------------------------------------
// Kernel 2: deterministic per-expert token lists
// ---------------------------------------------------------------------------
__global__ void build_lists(const int* __restrict__ tok_expert,
                            const float* __restrict__ tok_gatew,
                            int* __restrict__ counts, int* __restrict__ offsets,
                            int* __restrict__ row_token, float* __restrict__ row_gatew,
                            int* __restrict__ pair_row) {
    __shared__ int s_off[NE];
    __shared__ int s_cnt[NE];
    int e    = threadIdx.x >> 6;
    int lane = threadIdx.x & 63;
    unsigned long long lt = (1ull << lane) - 1ull;

    int cnt = 0;
    for (int base = 0; base < NPAIR; base += 64) {
        int id = tok_expert[base + lane];
        unsigned long long m = __ballot(id == e);
        cnt += __popcll(m);
    }
    if (lane == 0) s_cnt[e] = cnt;
    __syncthreads();
    if (threadIdx.x == 0) {
        int o = 0;
        for (int i = 0; i < NE; ++i) {
            int c = s_cnt[i];
            counts[i] = c; offsets[i] = o; s_off[i] = o; o += c;
        }
    }
    __syncthreads();

    int rbase = s_off[e];
    for (int base = 0; base < NPAIR; base += 64) {
        int entry = base + lane;
        int id = tok_expert[entry];
        bool match = (id == e);
        unsigned long long m = __ballot(match);
        int pre = __popcll(m & lt);
        if (match) {
            int row = rbase + pre;
            row_token[row] = entry >> 1;
            row_gatew[row] = tok_gatew[entry];
            pair_row[entry] = row;
        }
        rbase += __popcll(m);
    }
}

// ---------------------------------------------------------------------------
// Kernel 3 (production, = R10): H = silu(Xbf*w1) .* (Xbf*w3)
// ---------------------------------------------------------------------------
#define EP1(CUR, WS, LS, S, HAS_DMA, HAS_L, HAS_W, VMW) do {                  \
    if (HAS_DMA) {                                                            \
        async16(&As[CUR ^ 1][(size_t)t * 8], asrc0 + ((S) + 1) * BKE);        \
        if (t < 256)                                                          \
            async16(&As[CUR ^ 1][(size_t)(512 + t) * 8],                      \
                    asrc1 + ((S) + 1) * BKE);                                 \
    }                                                                         \
    SCHEDBAR;                                                                 \
    if (HAS_L) {                                                              \
        _Pragma("unroll")                                                     \
        for (int j = 0; j < 8; ++j)                                           \
            LS[j] = bsrc[(size_t)(((S) + 2) * BKE + j) * FF];                 \
    }                                                                         \
    SCHEDBAR;                                                                 \
    bf16x8 a_[3];                                                             \
    _Pragma("unroll")                                                         \
    for (int f = 0; f < 3; ++f) {                                             \
        int r_ = wm * 48 + f * 16 + l15;                                      \
        int p_ = (lg + (r_ >> 1)) & 3;                                        \
        a_[f] = *(const bf16x8*)&As[CUR][((size_t)r_ * 4 + p_) * 8];          \
    }                                                                         \
    _Pragma("unroll")                                                         \
    for (int nf = 0; nf < 2; ++nf) {                                          \
        int ch_ = wn * 32 + nf * 16 + l15 + lg * 64;                          \
        bf16x8 b1f = *(const bf16x8*)&Bs[CUR][0][ch_][0];                     \
        bf16x8 b3f = *(const bf16x8*)&Bs[CUR][1][ch_][0];                     \
        _Pragma("unroll")                                                     \
        for (int f = 0; f < 3; ++f) {                                         \
            acc1[f][nf] = MFMA16(a_[f], b1f, acc1[f][nf]);                    \
            acc3[f][nf] = MFMA16(a_[f], b3f, acc3[f][nf]);                    \
        }                                                                     \
    }                                                                         \
    if (HAS_W) {                                                              \
        bf16x8 wv;                                                            \
        _Pragma("unroll")                                                     \
        for (int j = 0; j < 8; ++j) wv[j] = f2bf(WS[j]);                      \
        *(bf16x8*)&Bs[CUR ^ 1][bmat][bch][0] = wv;                            \
    }                                                                         \
    VMW;                                                                      \
    LGKMBAR;                                                                  \
} while (0)

__global__ __launch_bounds__(512, 4) void ffn1(
    const unsigned short* __restrict__ xbf, const float* __restrict__ w1,
    const float* __restrict__ w3,
    const int* __restrict__ counts, const int* __restrict__ offsets,
    const int* __restrict__ row_token, unsigned short* __restrict__ Hbuf) {
    __shared__ __align__(16) unsigned short As[2][BM * 4 * 8];     // 24 KB
    __shared__ __align__(16) unsigned short Bs[2][2][256][8];      // 16 KB

    int bid = blockIdx.x;
    int e  = bid >> 6;
    int f0 = (bid & 63) * BN;

    int Me = counts[e];
    if (Me == 0) return;
    int off = offsets[e];

    int t = threadIdx.x;
    int lane = t & 63;
    int w = t >> 6;
    int wm = w >> 1, wn = w & 1;
    int l15 = lane & 15, lg = lane >> 4;

    const float* w1e = w1 + (size_t)e * DIM * FF + f0;
    const float* w3e = w3 + (size_t)e * DIM * FF + f0;

    int bmat = t >> 8;
    int bc   = t & 255;
    int bcol = bc & 63, blg = bc >> 6;
    const float* bsrc = (bmat ? w3e : w1e) + (size_t)(blg * 8) * FF + bcol;
    int bch = bcol + blg * 64;

    const int NST = DIM / BKE;

    for (int mb = 0; mb < Me; mb += BM) {
        __syncthreads();
        const unsigned short* asrc0;
        const unsigned short* asrc1;
        {
            int m0 = t >> 2, c0 = t & 3;
            int rl0 = mb + m0;
            int tok0 = row_token[off + ((rl0 < Me) ? rl0 : (Me - 1))];
            asrc0 = xbf + (size_t)tok0 * DIM + (((c0 - (m0 >> 1)) & 3) << 3);
            int i1 = 512 + t;
            int m1 = i1 >> 2, c1 = i1 & 3;
            int rl1 = mb + m1;
            int tok1 = row_token[off + ((rl1 < Me) ? rl1 : (Me - 1))];
            asrc1 = xbf + (size_t)tok1 * DIM + (((c1 - (m1 >> 1)) & 3) << 3);
        }

        f32x4 acc1[3][2], acc3[3][2];
#pragma unroll
        for (int f = 0; f < 3; ++f)
#pragma unroll
            for (int nf = 0; nf < 2; ++nf) {
                acc1[f][nf] = (f32x4){0.f, 0.f, 0.f, 0.f};
                acc3[f][nf] = (f32x4){0.f, 0.f, 0.f, 0.f};
            }

        float bX[8], bY[8];

        async16(&As[0][(size_t)t * 8], asrc0);
        if (t < 256) async16(&As[0][(size_t)(512 + t) * 8], asrc1);
        SCHEDBAR;
#pragma unroll
        for (int j = 0; j < 8; ++j) bX[j] = bsrc[(size_t)j * FF];
        {
            bf16x8 wv;
#pragma unroll
            for (int j = 0; j < 8; ++j) wv[j] = f2bf(bX[j]);
            *(bf16x8*)&Bs[0][bmat][bch][0] = wv;
        }
#pragma unroll
        for (int j = 0; j < 8; ++j) bX[j] = bsrc[(size_t)(BKE + j) * FF];
        LGKMBAR;

        for (int s = 0; s < NST - 2; s += 2) {
            EP1(0, bX, bY, s,     1, 1, 1, VMCNT8);
            EP1(1, bY, bX, s + 1, 1, 1, 1, VMCNT8);
        }
        EP1(0, bX, bY, NST - 2, 1, 0, 1, VMCNT0);
        EP1(1, bY, bX, NST - 1, 0, 0, 0, (void)0);

#pragma unroll
        for (int f = 0; f < 3; ++f)
#pragma unroll
            for (int nf = 0; nf < 2; ++nf)
#pragma unroll
                for (int r = 0; r < 4; ++r) {
                    int rl = mb + wm * 48 + f * 16 + lg * 4 + r;
                    if (rl < Me) {
                        float a1 = acc1[f][nf][r], a3 = acc3[f][nf][r];
                        float h = (a1 / (1.f + __expf(-a1))) * a3;
                        Hbuf[(size_t)(off + rl) * FF + f0 + wn * 32 + nf * 16 + l15] =
                            (unsigned short)f2bf(h);
                    }
                }
    }
}

// ---------------------------------------------------------------------------
// ffn1_diag<V>: ablation clone of ffn1 writing to dead scratch, 3 reps.
// V=1 full | V=2 no B-global-loads | V=3 no MFMA (sinks) | V=4 no s_barrier
// V=5 no A-DMA.
// ---------------------------------------------------------------------------
#define DG1(CUR, WS, LS, S, HAS_DMA, HAS_L, HAS_W, VMW) do {                  \
    if (V != 5 && (HAS_DMA)) {                                                \
        async16(&As[CUR ^ 1][(size_t)t * 8], asrc0 + ((S) + 1) * BKE);        \
        if (t < 256)                                                          \
            async16(&As[CUR ^ 1][(size_t)(512 + t) * 8],                      \
                    asrc1 + ((S) + 1) * BKE);                                 \
    }                                                                         \
    SCHEDBAR;                                                                 \
    if (V != 2 && (HAS_L)) {                                                  \
        _Pragma("unroll")                                                     \
        for (int j = 0; j < 8; ++j)                                           \
            LS[j] = bsrc[(size_t)(((S) + 2) * BKE + j) * FF];                 \
    }                                                                         \
    SCHEDBAR;                                                                 \
    bf16x8 a_[3];                                                             \
    _Pragma("unroll")                                                         \
    for (int f = 0; f < 3; ++f) {                                             \
        int r_ = wm * 48 + f * 16 + l15;                                      \
        int p_ = (lg + (r_ >> 1)) & 3;                                        \
        a_[f] = *(const bf16x8*)&As[CUR][((size_t)r_ * 4 + p_) * 8];          \
    }                                                                         \
    if (V == 3) { SINKV(a_[0]); SINKV(a_[1]); SINKV(a_[2]); }                 \
    _Pragma("unroll")                                                         \
    for (int nf = 0; nf < 2; ++nf) {                                          \
        int ch_ = wn * 32 + nf * 16 + l15 + lg * 64;                          \
        bf16x8 b1f = *(const bf16x8*)&Bs[CUR][0][ch_][0];                     \
        bf16x8 b3f = *(const bf16x8*)&Bs[CUR][1][ch_][0];                     \
        if (V == 3) { SINKV(b1f); SINKV(b3f); }                               \
        else {                                                                \
            _Pragma("unroll")                                                 \
            for (int f = 0; f < 3; ++f) {                                     \
                acc1[f][nf] = MFMA16(a_[f], b1f, acc1[f][nf]);                \
                acc3[f][nf] = MFMA16(a_[f], b3f, acc3[f][nf]);                \
            }                                                                 \
        }                                                                     \
    }                                                                         \
    if (HAS_W) {                                                              \
        bf16x8 wv;                                                            \
        _Pragma("unroll")                                                     \
        for (int j = 0; j < 8; ++j) wv[j] = f2bf(WS[j]);                      \
        *(bf16x8*)&Bs[CUR ^ 1][bmat][bch][0] = wv;                            \
    }                                                                         \
    if (V != 5) { VMW; }                                                      \
    if (V != 4) { LGKMBAR; } else { LGKMONLY; }                               \
} while (0)

template <int V>
__global__ __launch_bounds__(512, 4) void ffn1_diag(
    const unsigned short* __restrict__ xbf, const float* __restrict__ w1,
    const float* __restrict__ w3,
    const int* __restrict__ counts, const int* __restrict__ offsets,
    const int* __restrict__ row_token, unsigned short* __restrict__ Hout) {
    __shared__ __align__(16) unsigned short As[2][BM * 4 * 8];
    __shared__ __align__(16) unsigned short Bs[2][2][256][8];

    int bid = blockIdx.x;
    int e  = bid >> 6;
    int f0 = (bid & 63) * BN;

    int Me = counts[e];
    if (Me == 0) return;
    int off = offsets[e];

    int t = threadIdx.x;
    int lane = t & 63;
    int w = t >> 6;
    int wm = w >> 1, wn = w & 1;
    int l15 = lane & 15, lg = lane >> 4;

    const float* w1e = w1 + (size_t)e * DIM * FF + f0;
    const float* w3e = w3 + (size_t)e * DIM * FF + f0;

    int bmat = t >> 8;
    int bc   = t & 255;
    int bcol = bc & 63, blg = bc >> 6;
    const float* bsrc = (bmat ? w3e : w1e) + (size_t)(blg * 8) * FF + bcol;
    int bch = bcol + blg * 64;

    const int NST = DIM / BKE;

    for (int rep = 0; rep < 3; ++rep)
    for (int mb = 0; mb < Me; mb += BM) {
        __syncthreads();
        const unsigned short* asrc0;
        const unsigned short* asrc1;
        {
            int m0 = t >> 2, c0 = t & 3;
            int rl0 = mb + m0;
            int tok0 = row_token[off + ((rl0 < Me) ? rl0 : (Me - 1))];
            asrc0 = xbf + (size_t)tok0 * DIM + (((c0 - (m0 >> 1)) & 3) << 3);
            int i1 = 512 + t;
            int m1 = i1 >> 2, c1 = i1 & 3;
            int rl1 = mb + m1;
            int tok1 = row_token[off + ((rl1 < Me) ? rl1 : (Me - 1))];
            asrc1 = xbf + (size_t)tok1 * DIM + (((c1 - (m1 >> 1)) & 3) << 3);
        }

        f32x4 acc1[3][2], acc3[3][2];
#pragma unroll
        for (int f = 0; f < 3; ++f)
#pragma unroll
            for (int nf = 0; nf < 2; ++nf) {
                acc1[f][nf] = (f32x4){0.f, 0.f, 0.f, 0.f};
                acc3[f][nf] = (f32x4){0.f, 0.f, 0.f, 0.f};
            }

        float bX[8], bY[8];

        if (V != 5) {
            async16(&As[0][(size_t)t * 8], asrc0);
            if (t < 256) async16(&As[0][(size_t)(512 + t) * 8], asrc1);
        }
        SCHEDBAR;
#pragma unroll
        for (int j = 0; j < 8; ++j) bX[j] = bsrc[(size_t)j * FF];
        {
            bf16x8 wv;
#pragma unroll
            for (int j = 0; j < 8; ++j) wv[j] = f2bf(bX[j]);
            *(bf16x8*)&Bs[0][bmat][bch][0] = wv;
        }
#pragma unroll
        for (int j = 0; j < 8; ++j) bX[j] = bsrc[(size_t)(BKE + j) * FF];
        if (V != 4) { LGKMBAR; } else { LGKMONLY; }

        for (int s = 0; s < NST - 2; s += 2) {
            DG1(0, bX, bY, s,     1, 1, 1, VMCNT8);
            DG1(1, bY, bX, s + 1, 1, 1, 1, VMCNT8);
        }
        DG1(0, bX, bY, NST - 2, 1, 0, 1, VMCNT0);
        DG1(1, bY, bX, NST - 1, 0, 0, 0, (void)0);

#pragma unroll
        for (int f = 0; f < 3; ++f)
#pragma unroll
            for (int nf = 0; nf < 2; ++nf)
#pragma unroll
                for (int r = 0; r < 4; ++r) {
                    int rl = mb + wm * 48 + f * 16 + lg * 4 + r;
                    if (rl < Me) {
                        float a1 = acc1[f][nf][r], a3 = acc3[f][nf][r];
                        float h = (a1 / (1.f + __expf(-a1))) * a3;
                        Hout[(size_t)(off + rl) * FF + f0 + wn * 32 + nf * 16 + l15] =
                            (unsigned short)f2bf(h);
                    }
                }
    }
}

// ---------------------------------------------------------------------------
// Kernel 4 (production, = R10): OutPair = (H @ w2) * gate_weight
// ---------------------------------------------------------------------------
#define EP2(CUR, WS, LS, S, HAS_DMA, HAS_L, HAS_W, VMW) do {                  \
    if (HAS_DMA) {                                                            \
        async16(&As[CUR ^ 1][(size_t)t * 8], asrc0 + ((S) + 1) * BKE);        \
        if (t < 256)                                                          \
            async16(&As[CUR ^ 1][(size_t)(512 + t) * 8],                      \
                    asrc1 + ((S) + 1) * BKE);                                 \
    }                                                                         \
    SCHEDBAR;                                                                 \
    if (HAS_L) {                                                              \
        _Pragma("unroll")                                                     \
        for (int j = 0; j < 4; ++j)                                           \
            LS[j] = bsrc[(size_t)(((S) + 2) * BKE + j) * DIM];                \
    }                                                                         \
    SCHEDBAR;                                                                 \
    bf16x8 a_[3];                                                             \
    _Pragma("unroll")                                                         \
    for (int f = 0; f < 3; ++f) {                                             \
        int r_ = wm * 48 + f * 16 + l15;                                      \
        int p_ = (lg + (r_ >> 1)) & 3;                                        \
        a_[f] = *(const bf16x8*)&As[CUR][((size_t)r_ * 4 + p_) * 8];          \
    }                                                                         \
    _Pragma("unroll")                                                         \
    for (int nf = 0; nf < 2; ++nf) {                                          \
        int ch_ = wn * 32 + nf * 16 + l15 + lg * 64;                          \
        bf16x8 bw = *(const bf16x8*)&Bs[CUR][ch_][0];                         \
        _Pragma("unroll")                                                     \
        for (int f = 0; f < 3; ++f)                                           \
            acc[f][nf] = MFMA16(a_[f], bw, acc[f][nf]);                       \
    }                                                                         \
    if (HAS_W) {                                                              \
        bf16x4 wv;                                                            \
        _Pragma("unroll")                                                     \
        for (int j = 0; j < 4; ++j) wv[j] = f2bf(WS[j]);                      \
        *(bf16x4*)&Bs[CUR ^ 1][bch][bhalf * 4] = wv;                          \
    }                                                                         \
    VMW;                                                                      \
    LGKMBAR;                                                                  \
} while (0)

__global__ __launch_bounds__(512, 4) void ffn2(
    const unsigned short* __restrict__ Hbuf, const float* __restrict__ w2,
    const int* __restrict__ counts, const int* __restrict__ offsets,
    const float* __restrict__ row_gatew, float* __restrict__ OP) {
    __shared__ __align__(16) unsigned short As[2][BM * 4 * 8];     // 24 KB
    __shared__ __align__(16) unsigned short Bs[2][256][8];         //  8 KB

    int bid = blockIdx.x;
    int e  = bid >> 5;
    int d0 = (bid & 31) * BN;

    int Me = counts[e];
    if (Me == 0) return;
    int off = offsets[e];

    int t = threadIdx.x;
    int lane = t & 63;
    int w = t >> 6;
    int wm = w >> 1, wn = w & 1;
    int l15 = lane & 15, lg = lane >> 4;

    const float* w2e = w2 + (size_t)e * FF * DIM + d0;

    int bcol = t & 63, blg = (t >> 6) & 3, bhalf = t >> 8;
    const float* bsrc = w2e + (size_t)(blg * 8 + bhalf * 4) * DIM + bcol;
    int bch = bcol + blg * 64;

    const int NST = FF / BKE;

    for (int mb = 0; mb < Me; mb += BM) {
        __syncthreads();
        const unsigned short* asrc0;
        const unsigned short* asrc1;
        {
            int m0 = t >> 2, c0 = t & 3;
            int rl0 = mb + m0;
            asrc0 = Hbuf + (size_t)(off + ((rl0 < Me) ? rl0 : (Me - 1))) * FF
                         + (((c0 - (m0 >> 1)) & 3) << 3);
            int i1 = 512 + t;
            int m1 = i1 >> 2, c1 = i1 & 3;
            int rl1 = mb + m1;
            asrc1 = Hbuf + (size_t)(off + ((rl1 < Me) ? rl1 : (Me - 1))) * FF
                         + (((c1 - (m1 >> 1)) & 3) << 3);
        }

        f32x4 acc[3][2];
#pragma unroll
        for (int f = 0; f < 3; ++f)
#pragma unroll
            for (int nf = 0; nf < 2; ++nf) acc[f][nf] = (f32x4){0.f, 0.f, 0.f, 0.f};

        float bX[4], bY[4];

        async16(&As[0][(size_t)t * 8], asrc0);
        if (t < 256) async16(&As[0][(size_t)(512 + t) * 8], asrc1);
        SCHEDBAR;
#pragma unroll
        for (int j = 0; j < 4; ++j) bX[j] = bsrc[(size_t)j * DIM];
        {
            bf16x4 wv;
#pragma unroll
            for (int j = 0; j < 4; ++j) wv[j] = f2bf(bX[j]);
            *(bf16x4*)&Bs[0][bch][bhalf * 4] = wv;
        }
#pragma unroll
        for (int j = 0; j < 4; ++j) bX[j] = bsrc[(size_t)(BKE + j) * DIM];
        LGKMBAR;

        for (int s = 0; s < NST - 2; s += 2) {
            EP2(0, bX, bY, s,     1, 1, 1, VMCNT4);
            EP2(1, bY, bX, s + 1, 1, 1, 1, VMCNT4);
        }
        EP2(0, bX, bY, NST - 2, 1, 0, 1, VMCNT0);
        EP2(1, bY, bX, NST - 1, 0, 0, 0, (void)0);

#pragma unroll
        for (int f = 0; f < 3; ++f)
#pragma unroll
            for (int nf = 0; nf < 2; ++nf)
#pragma unroll
                for (int r = 0; r < 4; ++r) {
                    int rl = mb + wm * 48 + f * 16 + lg * 4 + r;
                    if (rl < Me) {
                        int grow = off + rl;
                        float g = row_gatew[grow];
                        OP[(size_t)grow * DIM + d0 + wn * 32 + nf * 16 + l15] =
                            acc[f][nf][r] * g;
                    }
                }
    }
}

// ---------------------------------------------------------------------------
// Kernel 5: out[token] = OP[pair0] + OP[pair1]
// ---------------------------------------------------------------------------
__global__ void combine(const float* __restrict__ OP, const int* __restrict__ pair_row,
                        float* __restrict__ out) {
    int idx = blockIdx.x * blockDim.x + threadIdx.x;
    int token = idx >> 9;
    int q = idx & 511;
    int r0 = pair_row[token * 2 + 0];
    int r1 = pair_row[token * 2 + 1];
    float4 a = *(const float4*)(OP + (size_t)r0 * DIM + q * 4);
    float4 b = *(const float4*)(OP + (size_t)r1 * DIM + q * 4);
    float4 o;
    o.x = a.x + b.x; o.y = a.y + b.y; o.z = a.z + b.z; o.w = a.w + b.w;
    *(float4*)(out + (size_t)token * DIM + q * 4) = o;
}

// ---------------------------------------------------------------------------
extern "C" void kernel_launch(void* const* d_in, const int* in_sizes, int n_in,
                              void* d_out, int out_size, void* d_ws, size_t ws_size,
                              hipStream_t stream) {
    const float* x  = (const float*)d_in[0];
    const float* gw = (const float*)d_in[1];
    const float* w1 = (const float*)d_in[2];
    const float* w3 = (const float*)d_in[3];
    const float* w2 = (const float*)d_in[4];
    float* out = (float*)d_out;

    char* ws = (char*)d_ws;
    unsigned short* Hbuf = (unsigned short*)ws;                 // 8 MB bf16 [1024][4096]
    float* OP            = (float*)(ws + 8388608);              // 8 MB f32  [1024][2048]
    unsigned short* xbf  = (unsigned short*)(ws + 16777216);    // 2 MB bf16 [512][2048]
    char* meta           = ws + 18874368;
    int*   tok_expert = (int*)(meta);
    float* tok_gatew  = (float*)(meta + 4096);
    int*   counts     = (int*)(meta + 8192);
    int*   offsets    = (int*)(meta + 8224);
    int*   row_token  = (int*)(meta + 8256);
    float* row_gatew  = (float*)(meta + 12352);
    int*   pair_row   = (int*)(meta + 16448);

    gate_topk<<<TOK, 64, 0, stream>>>(x, gw, xbf, tok_expert, tok_gatew);
    build_lists<<<1, 512, 0, stream>>>(tok_expert, tok_gatew, counts, offsets,
                                       row_token, row_gatew, pair_row);
    ffn1<<<NE * 64, 512, 0, stream>>>(xbf, w1, w3, counts, offsets, row_token, Hbuf);
    ffn2<<<NE * 32, 512, 0, stream>>>(Hbuf, w2, counts, offsets, row_gatew, OP);
    combine<<<1024, 256, 0, stream>>>(OP, pair_row, out);

    // ---- diagnostics (write into Hbuf, now dead; output already final) ----
    ffn1_diag<1><<<NE * 64, 512, 0, stream>>>(xbf, w1, w3, counts, offsets,
                                              row_token, Hbuf);
    ffn1_diag<2><<<NE * 64, 512, 0, stream>>>(xbf, w1, w3, counts, offsets,
                                              row_token, Hbuf);
    ffn1_diag<3><<<NE * 64, 512, 0, stream>>>(xbf, w1, w3, counts, offsets,
                                              row_token, Hbuf);
    ffn1_diag<4><<<NE * 64, 512, 0, stream>>>(xbf, w1, w3, counts, offsets,
                                              row_token, Hbuf);
    ffn1_diag<5><<<NE * 64, 512, 0, stream>>>(xbf, w1, w3, counts, offsets,
                                              row_token, Hbuf);
}

// Round 12
// 571.338 us; speedup vs baseline: 2.9913x; 2.9913x over previous
//
#include <hip/hip_runtime.h>
#include <hip/hip_bf16.h>
#include <cstdint>
#include <cstddef>

// Problem constants
#define NB   64
#define NS   8
#define DIM  2048
#define FF   4096
#define NE   8
#define TOK  512            // NB*NS
#define NPAIR 1024          // TOK*2

typedef __attribute__((ext_vector_type(4))) float f32x4;
typedef __attribute__((ext_vector_type(8))) short bf16x8;

#define MFMA16(a, b, c) __builtin_amdgcn_mfma_f32_16x16x32_bf16((a), (b), (c), 0, 0, 0)

// round-half-up fp32 -> bf16 (0.5 ulp)
static __device__ __forceinline__ short f2bf(float f) {
    unsigned u = __builtin_bit_cast(unsigned, f);
    return (short)((u + 0x8000u) >> 16);
}

// packed fp32x2 -> bf16x2 (RNE), 1 instruction
static __device__ __forceinline__ unsigned cvtpk(float lo, float hi) {
    unsigned r;
    asm("v_cvt_pk_bf16_f32 %0, %1, %2" : "=v"(r) : "v"(lo), "v"(hi));
    return r;
}
static __device__ __forceinline__ bf16x8 pack8(const float* v) {
    uint4 u;
    u.x = cvtpk(v[0], v[1]); u.y = cvtpk(v[2], v[3]);
    u.z = cvtpk(v[4], v[5]); u.w = cvtpk(v[6], v[7]);
    return __builtin_bit_cast(bf16x8, u);
}

// ---------------------------------------------------------------------------
// Kernel 1: gating (logits -> top-2 -> softmax) + x -> bf16 preconvert.
// ---------------------------------------------------------------------------
__global__ void gate_topk(const float* __restrict__ x, const float* __restrict__ gw,
                          unsigned short* __restrict__ xbf,
                          int* __restrict__ tok_expert, float* __restrict__ tok_gatew) {
    int token = blockIdx.x;
    int lane  = threadIdx.x;
    const float* xr = x + (size_t)token * DIM;

    float acc[NE];
#pragma unroll
    for (int e = 0; e < NE; ++e) acc[e] = 0.f;

    for (int d0 = lane * 8; d0 < DIM; d0 += 64 * 8) {
        float4 xa = *(const float4*)(xr + d0);
        float4 xb = *(const float4*)(xr + d0 + 4);
        bf16x8 v;
        v[0] = f2bf(xa.x); v[1] = f2bf(xa.y); v[2] = f2bf(xa.z); v[3] = f2bf(xa.w);
        v[4] = f2bf(xb.x); v[5] = f2bf(xb.y); v[6] = f2bf(xb.z); v[7] = f2bf(xb.w);
        *(bf16x8*)(xbf + (size_t)token * DIM + d0) = v;
#pragma unroll
        for (int j = 0; j < 8; ++j) {
            float xv = (j < 4) ? ((const float*)&xa)[j] : ((const float*)&xb)[j - 4];
            const float4* g = (const float4*)(gw + (size_t)(d0 + j) * NE);
            float4 g0 = g[0], g1 = g[1];
            acc[0] += xv * g0.x; acc[1] += xv * g0.y;
            acc[2] += xv * g0.z; acc[3] += xv * g0.w;
            acc[4] += xv * g1.x; acc[5] += xv * g1.y;
            acc[6] += xv * g1.z; acc[7] += xv * g1.w;
        }
    }
#pragma unroll
    for (int off = 32; off >= 1; off >>= 1) {
#pragma unroll
        for (int e = 0; e < NE; ++e) acc[e] += __shfl_down(acc[e], off);
    }
    if (lane == 0) {
        float b1 = -1e30f, b2 = -1e30f; int i1 = 0, i2 = 0;
#pragma unroll
        for (int e = 0; e < NE; ++e) {
            float v = acc[e];
            if (v > b1) { b2 = b1; i2 = i1; b1 = v; i1 = e; }
            else if (v > b2) { b2 = v; i2 = e; }
        }
        float t = __expf(b2 - b1);
        tok_expert[token * 2 + 0] = i1;
        tok_expert[token * 2 + 1] = i2;
        tok_gatew[token * 2 + 0] = 1.f / (1.f + t);
        tok_gatew[token * 2 + 1] = t / (1.f + t);
    }
}

// ---------------------------------------------------------------------------
// Kernel 2: deterministic per-expert token lists (wave-per-expert ballot scan)
// ---------------------------------------------------------------------------
__global__ void build_lists(const int* __restrict__ tok_expert,
                            const float* __restrict__ tok_gatew,
                            int* __restrict__ counts, int* __restrict__ offsets,
                            int* __restrict__ row_token, float* __restrict__ row_gatew,
                            int* __restrict__ pair_row) {
    __shared__ int s_off[NE];
    __shared__ int s_cnt[NE];
    int e    = threadIdx.x >> 6;
    int lane = threadIdx.x & 63;
    unsigned long long lt = (1ull << lane) - 1ull;

    int cnt = 0;
    for (int base = 0; base < NPAIR; base += 64) {
        int id = tok_expert[base + lane];
        unsigned long long m = __ballot(id == e);
        cnt += __popcll(m);
    }
    if (lane == 0) s_cnt[e] = cnt;
    __syncthreads();
    if (threadIdx.x == 0) {
        int o = 0;
        for (int i = 0; i < NE; ++i) {
            int c = s_cnt[i];
            counts[i] = c; offsets[i] = o; s_off[i] = o; o += c;
        }
    }
    __syncthreads();

    int rbase = s_off[e];
    for (int base = 0; base < NPAIR; base += 64) {
        int entry = base + lane;
        int id = tok_expert[entry];
        bool match = (id == e);
        unsigned long long m = __ballot(match);
        int pre = __popcll(m & lt);
        if (match) {
            int row = rbase + pre;
            row_token[row] = entry >> 1;
            row_gatew[row] = tok_gatew[entry];
            pair_row[entry] = row;
        }
        rbase += __popcll(m);
    }
}

// ---------------------------------------------------------------------------
// Kernel 3: H = silu(Xbf*w1) .* (Xbf*w3).
// BARRIER-FREE, LDS-FREE. grid = 8 experts x 256 col-strips of 16; block =
// 128 thr = 2 independent waves, each owning 96 rows x 16 cols (full M in
// registers => B read exactly once; no inter-wave sharing => no barriers).
// Per K-step (32): issue 6 A-frag gathers (L2-hot xbf) | cvt_pk-pack B(s)
// (waits B(s) only, leaves A flying) | issue B(s+1) 16 coalesced dwords |
// 12 MFMA (waits A, leaves B(s+1) flying). Latency covered by 12 waves/CU.
// ---------------------------------------------------------------------------
__global__ __launch_bounds__(128, 3) void ffn1(
    const unsigned short* __restrict__ xbf, const float* __restrict__ w1,
    const float* __restrict__ w3,
    const int* __restrict__ counts, const int* __restrict__ offsets,
    const int* __restrict__ row_token, unsigned short* __restrict__ Hbuf) {
    int bid = blockIdx.x;
    int e     = bid >> 8;            // 256 strips per expert
    int strip = bid & 255;
    int p0 = strip * 16;

    int Me = counts[e];
    if (Me == 0) return;
    int off = offsets[e];

    int t = threadIdx.x;
    int wv = t >> 6, lane = t & 63;
    int l15 = lane & 15, lg = lane >> 4;

    // per-lane B base: col p0+l15, k-rows lg*8 + j  (wave-coalesced 4x64B/instr)
    const float* b1p = w1 + (size_t)e * DIM * FF + (size_t)(lg * 8) * FF + p0 + l15;
    const float* b3p = w3 + (size_t)e * DIM * FF + (size_t)(lg * 8) * FF + p0 + l15;

    for (int mb = 0; mb < Me; mb += 192) {
        int rbase = mb + wv * 96;
        if (rbase < Me) {
            // A row pointers (per-lane; lg*8 k-offset folded in)
            const unsigned short* arow[6];
#pragma unroll
            for (int f = 0; f < 6; ++f) {
                int rl = rbase + f * 16 + l15;
                int rr = (rl < Me) ? rl : (Me - 1);
                arow[f] = xbf + (size_t)row_token[off + rr] * DIM + lg * 8;
            }

            f32x4 acc1[6], acc3[6];
#pragma unroll
            for (int f = 0; f < 6; ++f) {
                acc1[f] = (f32x4){0.f, 0.f, 0.f, 0.f};
                acc3[f] = (f32x4){0.f, 0.f, 0.f, 0.f};
            }

            float bR1[8], bR3[8];
            // prologue: B(0)
#pragma unroll
            for (int j = 0; j < 8; ++j) {
                bR1[j] = b1p[(size_t)j * FF];
                bR3[j] = b3p[(size_t)j * FF];
            }

            for (int s = 0; s < DIM / 32; ++s) {
                // 1) A(s) gathers (issued first so MFMA's wait leaves B(s+1) in flight)
                bf16x8 a[6];
#pragma unroll
                for (int f = 0; f < 6; ++f)
                    a[f] = *(const bf16x8*)(arow[f] + s * 32);
                // 2) pack B(s) (waits only on B(s), issued last iteration)
                bf16x8 b1f = pack8(bR1);
                bf16x8 b3f = pack8(bR3);
                // 3) issue B(s+1)
                if (s + 1 < DIM / 32) {
#pragma unroll
                    for (int j = 0; j < 8; ++j) {
                        bR1[j] = b1p[(size_t)((s + 1) * 32 + j) * FF];
                        bR3[j] = b3p[(size_t)((s + 1) * 32 + j) * FF];
                    }
                }
                // 4) MFMA
#pragma unroll
                for (int f = 0; f < 6; ++f) {
                    acc1[f] = MFMA16(a[f], b1f, acc1[f]);
                    acc3[f] = MFMA16(a[f], b3f, acc3[f]);
                }
            }

            // epilogue: silu(a1)*a3 -> bf16 H
#pragma unroll
            for (int f = 0; f < 6; ++f)
#pragma unroll
                for (int r = 0; r < 4; ++r) {
                    int rl = rbase + f * 16 + lg * 4 + r;
                    if (rl < Me) {
                        float a1 = acc1[f][r], a3 = acc3[f][r];
                        float h = (a1 / (1.f + __expf(-a1))) * a3;
                        Hbuf[(size_t)(off + rl) * FF + p0 + l15] =
                            (unsigned short)f2bf(h);
                    }
                }
        }
    }
}

// ---------------------------------------------------------------------------
// Kernel 4: OutPair = (H @ w2) * gate_weight.  Same barrier-free structure.
// grid = 8 experts x 128 d-strips of 16; block = 128 thr = 2 waves x 96 rows.
// ---------------------------------------------------------------------------
__global__ __launch_bounds__(128, 4) void ffn2(
    const unsigned short* __restrict__ Hbuf, const float* __restrict__ w2,
    const int* __restrict__ counts, const int* __restrict__ offsets,
    const float* __restrict__ row_gatew, float* __restrict__ OP) {
    int bid = blockIdx.x;
    int e     = bid >> 7;            // 128 strips per expert
    int strip = bid & 127;
    int d0 = strip * 16;

    int Me = counts[e];
    if (Me == 0) return;
    int off = offsets[e];

    int t = threadIdx.x;
    int wv = t >> 6, lane = t & 63;
    int l15 = lane & 15, lg = lane >> 4;

    const float* bp = w2 + (size_t)e * FF * DIM + (size_t)(lg * 8) * DIM + d0 + l15;

    for (int mb = 0; mb < Me; mb += 192) {
        int rbase = mb + wv * 96;
        if (rbase < Me) {
            const unsigned short* arow[6];
#pragma unroll
            for (int f = 0; f < 6; ++f) {
                int rl = rbase + f * 16 + l15;
                int rr = (rl < Me) ? rl : (Me - 1);
                arow[f] = Hbuf + (size_t)(off + rr) * FF + lg * 8;
            }

            f32x4 acc[6];
#pragma unroll
            for (int f = 0; f < 6; ++f) acc[f] = (f32x4){0.f, 0.f, 0.f, 0.f};

            float bR[8];
#pragma unroll
            for (int j = 0; j < 8; ++j) bR[j] = bp[(size_t)j * DIM];

            for (int s = 0; s < FF / 32; ++s) {
                bf16x8 a[6];
#pragma unroll
                for (int f = 0; f < 6; ++f)
                    a[f] = *(const bf16x8*)(arow[f] + s * 32);
                bf16x8 bf_ = pack8(bR);
                if (s + 1 < FF / 32) {
#pragma unroll
                    for (int j = 0; j < 8; ++j)
                        bR[j] = bp[(size_t)((s + 1) * 32 + j) * DIM];
                }
#pragma unroll
                for (int f = 0; f < 6; ++f)
                    acc[f] = MFMA16(a[f], bf_, acc[f]);
            }

#pragma unroll
            for (int f = 0; f < 6; ++f)
#pragma unroll
                for (int r = 0; r < 4; ++r) {
                    int rl = rbase + f * 16 + lg * 4 + r;
                    if (rl < Me) {
                        int grow = off + rl;
                        float g = row_gatew[grow];
                        OP[(size_t)grow * DIM + d0 + l15] = acc[f][r] * g;
                    }
                }
        }
    }
}

// ---------------------------------------------------------------------------
// Kernel 5: out[token] = OP[pair0] + OP[pair1]
// ---------------------------------------------------------------------------
__global__ void combine(const float* __restrict__ OP, const int* __restrict__ pair_row,
                        float* __restrict__ out) {
    int idx = blockIdx.x * blockDim.x + threadIdx.x;
    int token = idx >> 9;
    int q = idx & 511;
    int r0 = pair_row[token * 2 + 0];
    int r1 = pair_row[token * 2 + 1];
    float4 a = *(const float4*)(OP + (size_t)r0 * DIM + q * 4);
    float4 b = *(const float4*)(OP + (size_t)r1 * DIM + q * 4);
    float4 o;
    o.x = a.x + b.x; o.y = a.y + b.y; o.z = a.z + b.z; o.w = a.w + b.w;
    *(float4*)(out + (size_t)token * DIM + q * 4) = o;
}

// ---------------------------------------------------------------------------
extern "C" void kernel_launch(void* const* d_in, const int* in_sizes, int n_in,
                              void* d_out, int out_size, void* d_ws, size_t ws_size,
                              hipStream_t stream) {
    const float* x  = (const float*)d_in[0];
    const float* gw = (const float*)d_in[1];
    const float* w1 = (const float*)d_in[2];
    const float* w3 = (const float*)d_in[3];
    const float* w2 = (const float*)d_in[4];
    float* out = (float*)d_out;

    char* ws = (char*)d_ws;
    unsigned short* Hbuf = (unsigned short*)ws;                 // 8 MB bf16 [1024][4096]
    float* OP            = (float*)(ws + 8388608);              // 8 MB f32  [1024][2048]
    unsigned short* xbf  = (unsigned short*)(ws + 16777216);    // 2 MB bf16 [512][2048]
    char* meta           = ws + 18874368;
    int*   tok_expert = (int*)(meta);
    float* tok_gatew  = (float*)(meta + 4096);
    int*   counts     = (int*)(meta + 8192);
    int*   offsets    = (int*)(meta + 8224);
    int*   row_token  = (int*)(meta + 8256);
    float* row_gatew  = (float*)(meta + 12352);
    int*   pair_row   = (int*)(meta + 16448);

    gate_topk<<<TOK, 64, 0, stream>>>(x, gw, xbf, tok_expert, tok_gatew);
    build_lists<<<1, 512, 0, stream>>>(tok_expert, tok_gatew, counts, offsets,
                                       row_token, row_gatew, pair_row);
    ffn1<<<NE * 256, 128, 0, stream>>>(xbf, w1, w3, counts, offsets, row_token, Hbuf);
    ffn2<<<NE * 128, 128, 0, stream>>>(Hbuf, w2, counts, offsets, row_gatew, OP);
    combine<<<1024, 256, 0, stream>>>(OP, pair_row, out);
}

// Round 13
// 210.863 us; speedup vs baseline: 8.1051x; 2.7095x over previous
//
#include <hip/hip_runtime.h>
#include <hip/hip_bf16.h>
#include <cstdint>
#include <cstddef>

// Problem constants
#define NB   64
#define NS   8
#define DIM  2048
#define FF   4096
#define NE   8
#define TOK  512            // NB*NS
#define NPAIR 1024          // TOK*2

// GEMM tiling
#define BM   192            // 4 M-waves x 48 rows
#define BKE  32             // K per epoch
#define ASZ  (BM * 4 * 8)   // shorts per A LDS buffer (12 KB)

typedef __attribute__((ext_vector_type(4))) float f32x4;
typedef __attribute__((ext_vector_type(8))) short bf16x8;

#define MFMA16(a, b, c) __builtin_amdgcn_mfma_f32_16x16x32_bf16((a), (b), (c), 0, 0, 0)
#define SCHEDBAR __builtin_amdgcn_sched_barrier(0)
// barrier draining LDS only — vmcnt prefetches stay in flight across it
#define LGKMBAR do { asm volatile("s_waitcnt lgkmcnt(0)" ::: "memory"); \
                     asm volatile("s_barrier" ::: "memory");            \
                     __builtin_amdgcn_sched_barrier(0); } while (0)

// round-half-up fp32 -> bf16 (0.5 ulp)
static __device__ __forceinline__ short f2bf(float f) {
    unsigned u = __builtin_bit_cast(unsigned, f);
    return (short)((u + 0x8000u) >> 16);
}
// packed fp32x2 -> bf16x2 (RNE), 1 instruction
static __device__ __forceinline__ unsigned cvtpk(float lo, float hi) {
    unsigned r;
    asm("v_cvt_pk_bf16_f32 %0, %1, %2" : "=v"(r) : "v"(lo), "v"(hi));
    return r;
}
static __device__ __forceinline__ bf16x8 pack8(const float* v) {
    uint4 u;
    u.x = cvtpk(v[0], v[1]); u.y = cvtpk(v[2], v[3]);
    u.z = cvtpk(v[4], v[5]); u.w = cvtpk(v[6], v[7]);
    return __builtin_bit_cast(bf16x8, u);
}

static __device__ __forceinline__ void async16(void* l, const void* g) {
    __builtin_amdgcn_global_load_lds(
        (const __attribute__((address_space(1))) void*)g,
        (__attribute__((address_space(3))) void*)l, 16, 0, 0);
}

// ---------------------------------------------------------------------------
// Kernel 1: gating + x -> bf16 preconvert.
// ---------------------------------------------------------------------------
__global__ void gate_topk(const float* __restrict__ x, const float* __restrict__ gw,
                          unsigned short* __restrict__ xbf,
                          int* __restrict__ tok_expert, float* __restrict__ tok_gatew) {
    int token = blockIdx.x;
    int lane  = threadIdx.x;
    const float* xr = x + (size_t)token * DIM;

    float acc[NE];
#pragma unroll
    for (int e = 0; e < NE; ++e) acc[e] = 0.f;

    for (int d0 = lane * 8; d0 < DIM; d0 += 64 * 8) {
        float4 xa = *(const float4*)(xr + d0);
        float4 xb = *(const float4*)(xr + d0 + 4);
        bf16x8 v;
        v[0] = f2bf(xa.x); v[1] = f2bf(xa.y); v[2] = f2bf(xa.z); v[3] = f2bf(xa.w);
        v[4] = f2bf(xb.x); v[5] = f2bf(xb.y); v[6] = f2bf(xb.z); v[7] = f2bf(xb.w);
        *(bf16x8*)(xbf + (size_t)token * DIM + d0) = v;
#pragma unroll
        for (int j = 0; j < 8; ++j) {
            float xv = (j < 4) ? ((const float*)&xa)[j] : ((const float*)&xb)[j - 4];
            const float4* g = (const float4*)(gw + (size_t)(d0 + j) * NE);
            float4 g0 = g[0], g1 = g[1];
            acc[0] += xv * g0.x; acc[1] += xv * g0.y;
            acc[2] += xv * g0.z; acc[3] += xv * g0.w;
            acc[4] += xv * g1.x; acc[5] += xv * g1.y;
            acc[6] += xv * g1.z; acc[7] += xv * g1.w;
        }
    }
#pragma unroll
    for (int off = 32; off >= 1; off >>= 1) {
#pragma unroll
        for (int e = 0; e < NE; ++e) acc[e] += __shfl_down(acc[e], off);
    }
    if (lane == 0) {
        float b1 = -1e30f, b2 = -1e30f; int i1 = 0, i2 = 0;
#pragma unroll
        for (int e = 0; e < NE; ++e) {
            float v = acc[e];
            if (v > b1) { b2 = b1; i2 = i1; b1 = v; i1 = e; }
            else if (v > b2) { b2 = v; i2 = e; }
        }
        float t = __expf(b2 - b1);
        tok_expert[token * 2 + 0] = i1;
        tok_expert[token * 2 + 1] = i2;
        tok_gatew[token * 2 + 0] = 1.f / (1.f + t);
        tok_gatew[token * 2 + 1] = t / (1.f + t);
    }
}

// ---------------------------------------------------------------------------
// Kernel 2: deterministic per-expert token lists
// ---------------------------------------------------------------------------
__global__ void build_lists(const int* __restrict__ tok_expert,
                            const float* __restrict__ tok_gatew,
                            int* __restrict__ counts, int* __restrict__ offsets,
                            int* __restrict__ row_token, float* __restrict__ row_gatew,
                            int* __restrict__ pair_row) {
    __shared__ int s_off[NE];
    __shared__ int s_cnt[NE];
    int e    = threadIdx.x >> 6;
    int lane = threadIdx.x & 63;
    unsigned long long lt = (1ull << lane) - 1ull;

    int cnt = 0;
    for (int base = 0; base < NPAIR; base += 64) {
        int id = tok_expert[base + lane];
        unsigned long long m = __ballot(id == e);
        cnt += __popcll(m);
    }
    if (lane == 0) s_cnt[e] = cnt;
    __syncthreads();
    if (threadIdx.x == 0) {
        int o = 0;
        for (int i = 0; i < NE; ++i) {
            int c = s_cnt[i];
            counts[i] = c; offsets[i] = o; s_off[i] = o; o += c;
        }
    }
    __syncthreads();

    int rbase = s_off[e];
    for (int base = 0; base < NPAIR; base += 64) {
        int entry = base + lane;
        int id = tok_expert[entry];
        bool match = (id == e);
        unsigned long long m = __ballot(match);
        int pre = __popcll(m & lt);
        if (match) {
            int row = rbase + pre;
            row_token[row] = entry >> 1;
            row_gatew[row] = tok_gatew[entry];
            pair_row[entry] = row;
        }
        rbase += __popcll(m);
    }
}

// ---------------------------------------------------------------------------
// Kernel 3: H = silu(Xbf*w1) .* (Xbf*w3).
// grid = 256 (bid = tile*8 + e -> expert pinned to one XCD), 1024 thr =
// 4M x 4N waves, BN=128 (halves A re-read). A: DMA into TRIPLE-buffered LDS
// (distance-2); retirement is implicit via next epoch's pack8(B) register
// wait (FIFO: DMA(s+2) issued before B(s+2)). NO explicit vmcnt anywhere;
// barrier = lgkm-drain only. Every wait targets data >= 1 epoch old.
// ---------------------------------------------------------------------------
#define EP1(RD, WR, BSR, BSW, PACKV, LOADV, S, HAS_P, HAS_W) do {           \
    if (HAS_P) {                                                            \
        if (t < 768) async16(&(WR)[(size_t)t * 8], asrc0 + ((S) + 2) * BKE);\
    }                                                                       \
    SCHEDBAR;                                                               \
    if (HAS_P) {                                                            \
        _Pragma("unroll")                                                   \
        for (int j = 0; j < 8; ++j)                                         \
            LOADV[j] = bsrc[(size_t)(((S) + 2) * BKE + j) * FF];            \
    }                                                                       \
    SCHEDBAR;                                                               \
    bf16x8 a_[3];                                                           \
    _Pragma("unroll")                                                       \
    for (int f = 0; f < 3; ++f) {                                           \
        int r_ = wm * 48 + f * 16 + l15;                                    \
        int p_ = (lg + (r_ >> 1)) & 3;                                      \
        a_[f] = *(const bf16x8*)&(RD)[((size_t)r_ * 4 + p_) * 8];           \
    }                                                                       \
    _Pragma("unroll")                                                       \
    for (int nf = 0; nf < 2; ++nf) {                                        \
        int ch_ = wn * 32 + nf * 16 + l15 + lg * 128;                       \
        bf16x8 b1f = *(const bf16x8*)&Bs[BSR][0][ch_][0];                   \
        bf16x8 b3f = *(const bf16x8*)&Bs[BSR][1][ch_][0];                   \
        _Pragma("unroll")                                                   \
        for (int f = 0; f < 3; ++f) {                                       \
            acc1[f][nf] = MFMA16(a_[f], b1f, acc1[f][nf]);                  \
            acc3[f][nf] = MFMA16(a_[f], b3f, acc3[f][nf]);                  \
        }                                                                   \
    }                                                                       \
    if (HAS_W) {                                                            \
        bf16x8 wv = pack8(PACKV);                                           \
        *(bf16x8*)&Bs[BSW][bmat][bch][0] = wv;                              \
    }                                                                       \
    LGKMBAR;                                                                \
} while (0)

__global__ __launch_bounds__(1024, 4) void ffn1(
    const unsigned short* __restrict__ xbf, const float* __restrict__ w1,
    const float* __restrict__ w3,
    const int* __restrict__ counts, const int* __restrict__ offsets,
    const int* __restrict__ row_token, unsigned short* __restrict__ Hbuf) {
    __shared__ __align__(16) unsigned short As[3 * ASZ];           // 36 KB
    __shared__ __align__(16) unsigned short Bs[2][2][512][8];      // 32 KB

    int bid = blockIdx.x;
    int e  = bid & 7;                    // expert -> XCD (round-robin dispatch)
    int f0 = (bid >> 3) * 128;

    int Me = counts[e];
    if (Me == 0) return;
    int off = offsets[e];

    int t = threadIdx.x;
    int lane = t & 63;
    int w = t >> 6;
    int wm = w >> 2, wn = w & 3;         // 4 M-waves x 4 N-waves
    int l15 = lane & 15, lg = lane >> 4;

    const float* w1e = w1 + (size_t)e * DIM * FF + f0;
    const float* w3e = w3 + (size_t)e * DIM * FF + f0;

    // B role: one frag-chunk (8 k-strided fp32) per thread per epoch
    int bmat = t >> 9;
    int bc   = t & 511;
    int bcol = bc & 127, blg = bc >> 7;
    const float* bsrc = (bmat ? w3e : w1e) + (size_t)(blg * 8) * FF + bcol;
    int bch = bcol + blg * 128;

    const int NST = DIM / BKE;           // 64 epochs

    for (int mb = 0; mb < Me; mb += BM) {
        __syncthreads();
        // A DMA source (t<768): chunk i=t -> (m=i>>2, c=i&3); source chunk
        // (c-(m>>1))&3; read position (lg+(r>>1))&3  [R10-verified swizzle]
        const unsigned short* asrc0 = xbf;
        {
            int m0 = t >> 2, c0 = t & 3;
            int rl0 = mb + m0;
            int tok0 = row_token[off + ((rl0 < Me) ? rl0 : (Me - 1))];
            asrc0 = xbf + (size_t)tok0 * DIM + (((c0 - (m0 >> 1)) & 3) << 3);
        }

        f32x4 acc1[3][2], acc3[3][2];
#pragma unroll
        for (int f = 0; f < 3; ++f)
#pragma unroll
            for (int nf = 0; nf < 2; ++nf) {
                acc1[f][nf] = (f32x4){0.f, 0.f, 0.f, 0.f};
                acc3[f][nf] = (f32x4){0.f, 0.f, 0.f, 0.f};
            }

        unsigned short* pRd = As;
        unsigned short* pMd = As + ASZ;
        unsigned short* pWr = As + 2 * ASZ;

        float bX[8], bY[8];

        // prologue: DMA(0)->pRd, DMA(1)->pMd; B(0)->bX->Bs[0] (pack-wait
        // retires both DMAs, one-time); B(1)->bY
        if (t < 768) {
            async16(&pRd[(size_t)t * 8], asrc0);
            async16(&pMd[(size_t)t * 8], asrc0 + BKE);
        }
        SCHEDBAR;
#pragma unroll
        for (int j = 0; j < 8; ++j) bX[j] = bsrc[(size_t)j * FF];
        {
            bf16x8 wv = pack8(bX);
            *(bf16x8*)&Bs[0][bmat][bch][0] = wv;
        }
#pragma unroll
        for (int j = 0; j < 8; ++j) bY[j] = bsrc[(size_t)(BKE + j) * FF];
        LGKMBAR;

        for (int s = 0; s < NST - 2; s += 2) {
            EP1(pRd, pWr, 0, 1, bY, bX, s,     1, 1);
            EP1(pMd, pRd, 1, 0, bX, bY, s + 1, 1, 1);
            unsigned short* tt = pRd; pRd = pWr; pWr = pMd; pMd = tt;
        }
        EP1(pRd, pWr, 0, 1, bY, bX, NST - 2, 0, 1);
        EP1(pMd, pRd, 1, 0, bX, bY, NST - 1, 0, 0);

        // epilogue: silu(a1)*a3 -> bf16 H
#pragma unroll
        for (int f = 0; f < 3; ++f)
#pragma unroll
            for (int nf = 0; nf < 2; ++nf)
#pragma unroll
                for (int r = 0; r < 4; ++r) {
                    int rl = mb + wm * 48 + f * 16 + lg * 4 + r;
                    if (rl < Me) {
                        float a1 = acc1[f][nf][r], a3 = acc3[f][nf][r];
                        float h = (a1 / (1.f + __expf(-a1))) * a3;
                        Hbuf[(size_t)(off + rl) * FF + f0 + wn * 32 + nf * 16 + l15] =
                            (unsigned short)f2bf(h);
                    }
                }
    }
}

// ---------------------------------------------------------------------------
// Kernel 4: OutPair = (H @ w2) * gate_weight.  grid = 256 (bid = tile*8+e),
// 512 thr = 4M x 2N waves, BN=64.  Same zero-vmcnt triple-buffer pipeline.
// ---------------------------------------------------------------------------
#define EP2(RD, WR, BSR, BSW, PACKV, LOADV, S, HAS_P, HAS_W) do {           \
    if (HAS_P) {                                                            \
        async16(&(WR)[(size_t)t * 8], asrc0 + ((S) + 2) * BKE);             \
        if (t < 256)                                                        \
            async16(&(WR)[(size_t)(512 + t) * 8], asrc1 + ((S) + 2) * BKE); \
    }                                                                       \
    SCHEDBAR;                                                               \
    if (HAS_P) {                                                            \
        _Pragma("unroll")                                                   \
        for (int j = 0; j < 4; ++j)                                         \
            LOADV[j] = bsrc[(size_t)(((S) + 2) * BKE + j) * DIM];           \
    }                                                                       \
    SCHEDBAR;                                                               \
    bf16x8 a_[3];                                                           \
    _Pragma("unroll")                                                       \
    for (int f = 0; f < 3; ++f) {                                           \
        int r_ = wm * 48 + f * 16 + l15;                                    \
        int p_ = (lg + (r_ >> 1)) & 3;                                      \
        a_[f] = *(const bf16x8*)&(RD)[((size_t)r_ * 4 + p_) * 8];           \
    }                                                                       \
    _Pragma("unroll")                                                       \
    for (int nf = 0; nf < 2; ++nf) {                                        \
        int ch_ = wn * 32 + nf * 16 + l15 + lg * 64;                        \
        bf16x8 bw = *(const bf16x8*)&Bs[BSR][ch_][0];                       \
        _Pragma("unroll")                                                   \
        for (int f = 0; f < 3; ++f)                                         \
            acc[f][nf] = MFMA16(a_[f], bw, acc[f][nf]);                     \
    }                                                                       \
    if (HAS_W) {                                                            \
        uint2 u_;                                                           \
        u_.x = cvtpk(PACKV[0], PACKV[1]);                                   \
        u_.y = cvtpk(PACKV[2], PACKV[3]);                                   \
        *(uint2*)&Bs[BSW][bch][bhalf * 4] = u_;                             \
    }                                                                       \
    LGKMBAR;                                                                \
} while (0)

__global__ __launch_bounds__(512, 4) void ffn2(
    const unsigned short* __restrict__ Hbuf, const float* __restrict__ w2,
    const int* __restrict__ counts, const int* __restrict__ offsets,
    const float* __restrict__ row_gatew, float* __restrict__ OP) {
    __shared__ __align__(16) unsigned short As[3 * ASZ];           // 36 KB
    __shared__ __align__(16) unsigned short Bs[2][256][8];         //  8 KB

    int bid = blockIdx.x;
    int e  = bid & 7;
    int d0 = (bid >> 3) * 64;

    int Me = counts[e];
    if (Me == 0) return;
    int off = offsets[e];

    int t = threadIdx.x;
    int lane = t & 63;
    int w = t >> 6;
    int wm = w >> 1, wn = w & 1;
    int l15 = lane & 15, lg = lane >> 4;

    const float* w2e = w2 + (size_t)e * FF * DIM + d0;

    // B role: half frag-chunk (4 k-strided fp32) per thread per epoch
    int bcol = t & 63, blg = (t >> 6) & 3, bhalf = t >> 8;
    const float* bsrc = w2e + (size_t)(blg * 8 + bhalf * 4) * DIM + bcol;
    int bch = bcol + blg * 64;

    const int NST = FF / BKE;            // 128 epochs

    for (int mb = 0; mb < Me; mb += BM) {
        __syncthreads();
        const unsigned short* asrc0;
        const unsigned short* asrc1;
        {
            int m0 = t >> 2, c0 = t & 3;
            int rl0 = mb + m0;
            asrc0 = Hbuf + (size_t)(off + ((rl0 < Me) ? rl0 : (Me - 1))) * FF
                         + (((c0 - (m0 >> 1)) & 3) << 3);
            int i1 = 512 + t;
            int m1 = i1 >> 2, c1 = i1 & 3;
            int rl1 = mb + m1;
            asrc1 = Hbuf + (size_t)(off + ((rl1 < Me) ? rl1 : (Me - 1))) * FF
                         + (((c1 - (m1 >> 1)) & 3) << 3);
        }

        f32x4 acc[3][2];
#pragma unroll
        for (int f = 0; f < 3; ++f)
#pragma unroll
            for (int nf = 0; nf < 2; ++nf) acc[f][nf] = (f32x4){0.f, 0.f, 0.f, 0.f};

        unsigned short* pRd = As;
        unsigned short* pMd = As + ASZ;
        unsigned short* pWr = As + 2 * ASZ;

        float bX[4], bY[4];

        // prologue
        async16(&pRd[(size_t)t * 8], asrc0);
        if (t < 256) async16(&pRd[(size_t)(512 + t) * 8], asrc1);
        async16(&pMd[(size_t)t * 8], asrc0 + BKE);
        if (t < 256) async16(&pMd[(size_t)(512 + t) * 8], asrc1 + BKE);
        SCHEDBAR;
#pragma unroll
        for (int j = 0; j < 4; ++j) bX[j] = bsrc[(size_t)j * DIM];
        {
            uint2 u_;
            u_.x = cvtpk(bX[0], bX[1]);
            u_.y = cvtpk(bX[2], bX[3]);
            *(uint2*)&Bs[0][bch][bhalf * 4] = u_;
        }
#pragma unroll
        for (int j = 0; j < 4; ++j) bY[j] = bsrc[(size_t)(BKE + j) * DIM];
        LGKMBAR;

        for (int s = 0; s < NST - 2; s += 2) {
            EP2(pRd, pWr, 0, 1, bY, bX, s,     1, 1);
            EP2(pMd, pRd, 1, 0, bX, bY, s + 1, 1, 1);
            unsigned short* tt = pRd; pRd = pWr; pWr = pMd; pMd = tt;
        }
        EP2(pRd, pWr, 0, 1, bY, bX, NST - 2, 0, 1);
        EP2(pMd, pRd, 1, 0, bX, bY, NST - 1, 0, 0);

#pragma unroll
        for (int f = 0; f < 3; ++f)
#pragma unroll
            for (int nf = 0; nf < 2; ++nf)
#pragma unroll
                for (int r = 0; r < 4; ++r) {
                    int rl = mb + wm * 48 + f * 16 + lg * 4 + r;
                    if (rl < Me) {
                        int grow = off + rl;
                        float g = row_gatew[grow];
                        OP[(size_t)grow * DIM + d0 + wn * 32 + nf * 16 + l15] =
                            acc[f][nf][r] * g;
                    }
                }
    }
}

// ---------------------------------------------------------------------------
// Kernel 5: out[token] = OP[pair0] + OP[pair1]
// ---------------------------------------------------------------------------
__global__ void combine(const float* __restrict__ OP, const int* __restrict__ pair_row,
                        float* __restrict__ out) {
    int idx = blockIdx.x * blockDim.x + threadIdx.x;
    int token = idx >> 9;
    int q = idx & 511;
    int r0 = pair_row[token * 2 + 0];
    int r1 = pair_row[token * 2 + 1];
    float4 a = *(const float4*)(OP + (size_t)r0 * DIM + q * 4);
    float4 b = *(const float4*)(OP + (size_t)r1 * DIM + q * 4);
    float4 o;
    o.x = a.x + b.x; o.y = a.y + b.y; o.z = a.z + b.z; o.w = a.w + b.w;
    *(float4*)(out + (size_t)token * DIM + q * 4) = o;
}

// ---------------------------------------------------------------------------
extern "C" void kernel_launch(void* const* d_in, const int* in_sizes, int n_in,
                              void* d_out, int out_size, void* d_ws, size_t ws_size,
                              hipStream_t stream) {
    const float* x  = (const float*)d_in[0];
    const float* gw = (const float*)d_in[1];
    const float* w1 = (const float*)d_in[2];
    const float* w3 = (const float*)d_in[3];
    const float* w2 = (const float*)d_in[4];
    float* out = (float*)d_out;

    char* ws = (char*)d_ws;
    unsigned short* Hbuf = (unsigned short*)ws;                 // 8 MB bf16 [1024][4096]
    float* OP            = (float*)(ws + 8388608);              // 8 MB f32  [1024][2048]
    unsigned short* xbf  = (unsigned short*)(ws + 16777216);    // 2 MB bf16 [512][2048]
    char* meta           = ws + 18874368;
    int*   tok_expert = (int*)(meta);
    float* tok_gatew  = (float*)(meta + 4096);
    int*   counts     = (int*)(meta + 8192);
    int*   offsets    = (int*)(meta + 8224);
    int*   row_token  = (int*)(meta + 8256);
    float* row_gatew  = (float*)(meta + 12352);
    int*   pair_row   = (int*)(meta + 16448);

    gate_topk<<<TOK, 64, 0, stream>>>(x, gw, xbf, tok_expert, tok_gatew);
    build_lists<<<1, 512, 0, stream>>>(tok_expert, tok_gatew, counts, offsets,
                                       row_token, row_gatew, pair_row);
    ffn1<<<NE * 32, 1024, 0, stream>>>(xbf, w1, w3, counts, offsets, row_token, Hbuf);
    ffn2<<<NE * 32, 512, 0, stream>>>(Hbuf, w2, counts, offsets, row_gatew, OP);
    combine<<<1024, 256, 0, stream>>>(OP, pair_row, out);
}

// Round 14
// 198.559 us; speedup vs baseline: 8.6073x; 1.0620x over previous
//
#include <hip/hip_runtime.h>
#include <hip/hip_bf16.h>
#include <cstdint>
#include <cstddef>

// Problem constants
#define NB   64
#define NS   8
#define DIM  2048
#define FF   4096
#define NE   8
#define TOK  512            // NB*NS
#define NPAIR 1024          // TOK*2

// GEMM tiling
#define BM   192            // 4 M-waves x 48 rows
#define BKE  32             // K per epoch
#define ASZ  (BM * 4 * 8)   // shorts per A LDS buffer (12 KB)

typedef __attribute__((ext_vector_type(4))) float f32x4;
typedef __attribute__((ext_vector_type(8))) short bf16x8;

#define MFMA16(a, b, c) __builtin_amdgcn_mfma_f32_16x16x32_bf16((a), (b), (c), 0, 0, 0)
#define SCHEDBAR __builtin_amdgcn_sched_barrier(0)
// barrier draining LDS only — vmcnt prefetches stay in flight across it
#define LGKMBAR do { asm volatile("s_waitcnt lgkmcnt(0)" ::: "memory"); \
                     asm volatile("s_barrier" ::: "memory");            \
                     __builtin_amdgcn_sched_barrier(0); } while (0)

// round-half-up fp32 -> bf16 (0.5 ulp)
static __device__ __forceinline__ short f2bf(float f) {
    unsigned u = __builtin_bit_cast(unsigned, f);
    return (short)((u + 0x8000u) >> 16);
}
// packed fp32x2 -> bf16x2 (RNE), 1 instruction
static __device__ __forceinline__ unsigned cvtpk(float lo, float hi) {
    unsigned r;
    asm("v_cvt_pk_bf16_f32 %0, %1, %2" : "=v"(r) : "v"(lo), "v"(hi));
    return r;
}
static __device__ __forceinline__ bf16x8 pack8(const float* v) {
    uint4 u;
    u.x = cvtpk(v[0], v[1]); u.y = cvtpk(v[2], v[3]);
    u.z = cvtpk(v[4], v[5]); u.w = cvtpk(v[6], v[7]);
    return __builtin_bit_cast(bf16x8, u);
}

static __device__ __forceinline__ void async16(void* l, const void* g) {
    __builtin_amdgcn_global_load_lds(
        (const __attribute__((address_space(1))) void*)g,
        (__attribute__((address_space(3))) void*)l, 16, 0, 0);
}

// ---------------------------------------------------------------------------
// Kernel 1: gating + x -> bf16 preconvert.
// ---------------------------------------------------------------------------
__global__ void gate_topk(const float* __restrict__ x, const float* __restrict__ gw,
                          unsigned short* __restrict__ xbf,
                          int* __restrict__ tok_expert, float* __restrict__ tok_gatew) {
    int token = blockIdx.x;
    int lane  = threadIdx.x;
    const float* xr = x + (size_t)token * DIM;

    float acc[NE];
#pragma unroll
    for (int e = 0; e < NE; ++e) acc[e] = 0.f;

    for (int d0 = lane * 8; d0 < DIM; d0 += 64 * 8) {
        float4 xa = *(const float4*)(xr + d0);
        float4 xb = *(const float4*)(xr + d0 + 4);
        bf16x8 v;
        v[0] = f2bf(xa.x); v[1] = f2bf(xa.y); v[2] = f2bf(xa.z); v[3] = f2bf(xa.w);
        v[4] = f2bf(xb.x); v[5] = f2bf(xb.y); v[6] = f2bf(xb.z); v[7] = f2bf(xb.w);
        *(bf16x8*)(xbf + (size_t)token * DIM + d0) = v;
#pragma unroll
        for (int j = 0; j < 8; ++j) {
            float xv = (j < 4) ? ((const float*)&xa)[j] : ((const float*)&xb)[j - 4];
            const float4* g = (const float4*)(gw + (size_t)(d0 + j) * NE);
            float4 g0 = g[0], g1 = g[1];
            acc[0] += xv * g0.x; acc[1] += xv * g0.y;
            acc[2] += xv * g0.z; acc[3] += xv * g0.w;
            acc[4] += xv * g1.x; acc[5] += xv * g1.y;
            acc[6] += xv * g1.z; acc[7] += xv * g1.w;
        }
    }
#pragma unroll
    for (int off = 32; off >= 1; off >>= 1) {
#pragma unroll
        for (int e = 0; e < NE; ++e) acc[e] += __shfl_down(acc[e], off);
    }
    if (lane == 0) {
        float b1 = -1e30f, b2 = -1e30f; int i1 = 0, i2 = 0;
#pragma unroll
        for (int e = 0; e < NE; ++e) {
            float v = acc[e];
            if (v > b1) { b2 = b1; i2 = i1; b1 = v; i1 = e; }
            else if (v > b2) { b2 = v; i2 = e; }
        }
        float t = __expf(b2 - b1);
        tok_expert[token * 2 + 0] = i1;
        tok_expert[token * 2 + 1] = i2;
        tok_gatew[token * 2 + 0] = 1.f / (1.f + t);
        tok_gatew[token * 2 + 1] = t / (1.f + t);
    }
}

// ---------------------------------------------------------------------------
// Kernel 2: deterministic per-expert token lists
// ---------------------------------------------------------------------------
__global__ void build_lists(const int* __restrict__ tok_expert,
                            const float* __restrict__ tok_gatew,
                            int* __restrict__ counts, int* __restrict__ offsets,
                            int* __restrict__ row_token, float* __restrict__ row_gatew,
                            int* __restrict__ pair_row) {
    __shared__ int s_off[NE];
    __shared__ int s_cnt[NE];
    int e    = threadIdx.x >> 6;
    int lane = threadIdx.x & 63;
    unsigned long long lt = (1ull << lane) - 1ull;

    int cnt = 0;
    for (int base = 0; base < NPAIR; base += 64) {
        int id = tok_expert[base + lane];
        unsigned long long m = __ballot(id == e);
        cnt += __popcll(m);
    }
    if (lane == 0) s_cnt[e] = cnt;
    __syncthreads();
    if (threadIdx.x == 0) {
        int o = 0;
        for (int i = 0; i < NE; ++i) {
            int c = s_cnt[i];
            counts[i] = c; offsets[i] = o; s_off[i] = o; o += c;
        }
    }
    __syncthreads();

    int rbase = s_off[e];
    for (int base = 0; base < NPAIR; base += 64) {
        int entry = base + lane;
        int id = tok_expert[entry];
        bool match = (id == e);
        unsigned long long m = __ballot(match);
        int pre = __popcll(m & lt);
        if (match) {
            int row = rbase + pre;
            row_token[row] = entry >> 1;
            row_gatew[row] = tok_gatew[entry];
            pair_row[entry] = row;
        }
        rbase += __popcll(m);
    }
}

// ---------------------------------------------------------------------------
// Kernel 3 (= R13): H = silu(Xbf*w1) .* (Xbf*w3).
// grid = 256 (bid = tile*8 + e -> expert pinned to one XCD), 1024 thr =
// 4M x 4N waves, BN=128. A: DMA into TRIPLE-buffered LDS (distance-2);
// retirement implicit via next epoch's pack8(B) register wait. No explicit
// vmcnt; barrier = lgkm-drain only.
// ---------------------------------------------------------------------------
#define EP1(RD, WR, BSR, BSW, PACKV, LOADV, S, HAS_P, HAS_W) do {           \
    if (HAS_P) {                                                            \
        if (t < 768) async16(&(WR)[(size_t)t * 8], asrc0 + ((S) + 2) * BKE);\
    }                                                                       \
    SCHEDBAR;                                                               \
    if (HAS_P) {                                                            \
        _Pragma("unroll")                                                   \
        for (int j = 0; j < 8; ++j)                                         \
            LOADV[j] = bsrc[(size_t)(((S) + 2) * BKE + j) * FF];            \
    }                                                                       \
    SCHEDBAR;                                                               \
    bf16x8 a_[3];                                                           \
    _Pragma("unroll")                                                       \
    for (int f = 0; f < 3; ++f) {                                           \
        int r_ = wm * 48 + f * 16 + l15;                                    \
        int p_ = (lg + (r_ >> 1)) & 3;                                      \
        a_[f] = *(const bf16x8*)&(RD)[((size_t)r_ * 4 + p_) * 8];           \
    }                                                                       \
    _Pragma("unroll")                                                       \
    for (int nf = 0; nf < 2; ++nf) {                                        \
        int ch_ = wn * 32 + nf * 16 + l15 + lg * 128;                       \
        bf16x8 b1f = *(const bf16x8*)&Bs[BSR][0][ch_][0];                   \
        bf16x8 b3f = *(const bf16x8*)&Bs[BSR][1][ch_][0];                   \
        _Pragma("unroll")                                                   \
        for (int f = 0; f < 3; ++f) {                                       \
            acc1[f][nf] = MFMA16(a_[f], b1f, acc1[f][nf]);                  \
            acc3[f][nf] = MFMA16(a_[f], b3f, acc3[f][nf]);                  \
        }                                                                   \
    }                                                                       \
    if (HAS_W) {                                                            \
        bf16x8 wv = pack8(PACKV);                                           \
        *(bf16x8*)&Bs[BSW][bmat][bch][0] = wv;                              \
    }                                                                       \
    LGKMBAR;                                                                \
} while (0)

__global__ __launch_bounds__(1024, 4) void ffn1(
    const unsigned short* __restrict__ xbf, const float* __restrict__ w1,
    const float* __restrict__ w3,
    const int* __restrict__ counts, const int* __restrict__ offsets,
    const int* __restrict__ row_token, unsigned short* __restrict__ Hbuf) {
    __shared__ __align__(16) unsigned short As[3 * ASZ];           // 36 KB
    __shared__ __align__(16) unsigned short Bs[2][2][512][8];      // 32 KB

    int bid = blockIdx.x;
    int e  = bid & 7;                    // expert -> XCD (round-robin dispatch)
    int f0 = (bid >> 3) * 128;

    int Me = counts[e];
    if (Me == 0) return;
    int off = offsets[e];

    int t = threadIdx.x;
    int lane = t & 63;
    int w = t >> 6;
    int wm = w >> 2, wn = w & 3;         // 4 M-waves x 4 N-waves
    int l15 = lane & 15, lg = lane >> 4;

    const float* w1e = w1 + (size_t)e * DIM * FF + f0;
    const float* w3e = w3 + (size_t)e * DIM * FF + f0;

    int bmat = t >> 9;
    int bc   = t & 511;
    int bcol = bc & 127, blg = bc >> 7;
    const float* bsrc = (bmat ? w3e : w1e) + (size_t)(blg * 8) * FF + bcol;
    int bch = bcol + blg * 128;

    const int NST = DIM / BKE;           // 64 epochs

    for (int mb = 0; mb < Me; mb += BM) {
        __syncthreads();
        const unsigned short* asrc0 = xbf;
        {
            int m0 = t >> 2, c0 = t & 3;
            int rl0 = mb + m0;
            int tok0 = row_token[off + ((rl0 < Me) ? rl0 : (Me - 1))];
            asrc0 = xbf + (size_t)tok0 * DIM + (((c0 - (m0 >> 1)) & 3) << 3);
        }

        f32x4 acc1[3][2], acc3[3][2];
#pragma unroll
        for (int f = 0; f < 3; ++f)
#pragma unroll
            for (int nf = 0; nf < 2; ++nf) {
                acc1[f][nf] = (f32x4){0.f, 0.f, 0.f, 0.f};
                acc3[f][nf] = (f32x4){0.f, 0.f, 0.f, 0.f};
            }

        unsigned short* pRd = As;
        unsigned short* pMd = As + ASZ;
        unsigned short* pWr = As + 2 * ASZ;

        float bX[8], bY[8];

        if (t < 768) {
            async16(&pRd[(size_t)t * 8], asrc0);
            async16(&pMd[(size_t)t * 8], asrc0 + BKE);
        }
        SCHEDBAR;
#pragma unroll
        for (int j = 0; j < 8; ++j) bX[j] = bsrc[(size_t)j * FF];
        {
            bf16x8 wv = pack8(bX);
            *(bf16x8*)&Bs[0][bmat][bch][0] = wv;
        }
#pragma unroll
        for (int j = 0; j < 8; ++j) bY[j] = bsrc[(size_t)(BKE + j) * FF];
        LGKMBAR;

        for (int s = 0; s < NST - 2; s += 2) {
            EP1(pRd, pWr, 0, 1, bY, bX, s,     1, 1);
            EP1(pMd, pRd, 1, 0, bX, bY, s + 1, 1, 1);
            unsigned short* tt = pRd; pRd = pWr; pWr = pMd; pMd = tt;
        }
        EP1(pRd, pWr, 0, 1, bY, bX, NST - 2, 0, 1);
        EP1(pMd, pRd, 1, 0, bX, bY, NST - 1, 0, 0);

#pragma unroll
        for (int f = 0; f < 3; ++f)
#pragma unroll
            for (int nf = 0; nf < 2; ++nf)
#pragma unroll
                for (int r = 0; r < 4; ++r) {
                    int rl = mb + wm * 48 + f * 16 + lg * 4 + r;
                    if (rl < Me) {
                        float a1 = acc1[f][nf][r], a3 = acc3[f][nf][r];
                        float h = (a1 / (1.f + __expf(-a1))) * a3;
                        Hbuf[(size_t)(off + rl) * FF + f0 + wn * 32 + nf * 16 + l15] =
                            (unsigned short)f2bf(h);
                    }
                }
    }
}

// ---------------------------------------------------------------------------
// Kernel 4: OutPair partial = (H @ w2[K-half]) * gate_weight.
// K-SPLIT x2: grid = 512 (bid = (tile*2+ks)*8 + e), 2 blocks/CU -> barrier
// stalls of one block overlap with the co-resident block. Each block streams
// its w2 K-half exactly once (no duplicated B traffic). Partials -> OPa/OPb.
// ---------------------------------------------------------------------------
#define EP2(RD, WR, BSR, BSW, PACKV, LOADV, S, HAS_P, HAS_W) do {           \
    if (HAS_P) {                                                            \
        async16(&(WR)[(size_t)t * 8], asrc0 + ((S) + 2) * BKE);             \
        if (t < 256)                                                        \
            async16(&(WR)[(size_t)(512 + t) * 8], asrc1 + ((S) + 2) * BKE); \
    }                                                                       \
    SCHEDBAR;                                                               \
    if (HAS_P) {                                                            \
        _Pragma("unroll")                                                   \
        for (int j = 0; j < 4; ++j)                                         \
            LOADV[j] = bsrc[(size_t)(((S) + 2) * BKE + j) * DIM];           \
    }                                                                       \
    SCHEDBAR;                                                               \
    bf16x8 a_[3];                                                           \
    _Pragma("unroll")                                                       \
    for (int f = 0; f < 3; ++f) {                                           \
        int r_ = wm * 48 + f * 16 + l15;                                    \
        int p_ = (lg + (r_ >> 1)) & 3;                                      \
        a_[f] = *(const bf16x8*)&(RD)[((size_t)r_ * 4 + p_) * 8];           \
    }                                                                       \
    _Pragma("unroll")                                                       \
    for (int nf = 0; nf < 2; ++nf) {                                        \
        int ch_ = wn * 32 + nf * 16 + l15 + lg * 64;                        \
        bf16x8 bw = *(const bf16x8*)&Bs[BSR][ch_][0];                       \
        _Pragma("unroll")                                                   \
        for (int f = 0; f < 3; ++f)                                         \
            acc[f][nf] = MFMA16(a_[f], bw, acc[f][nf]);                     \
    }                                                                       \
    if (HAS_W) {                                                            \
        uint2 u_;                                                           \
        u_.x = cvtpk(PACKV[0], PACKV[1]);                                   \
        u_.y = cvtpk(PACKV[2], PACKV[3]);                                   \
        *(uint2*)&Bs[BSW][bch][bhalf * 4] = u_;                             \
    }                                                                       \
    LGKMBAR;                                                                \
} while (0)

__global__ __launch_bounds__(512, 4) void ffn2(
    const unsigned short* __restrict__ Hbuf, const float* __restrict__ w2,
    const int* __restrict__ counts, const int* __restrict__ offsets,
    const float* __restrict__ row_gatew,
    float* __restrict__ OPa, float* __restrict__ OPb) {
    __shared__ __align__(16) unsigned short As[3 * ASZ];           // 36 KB
    __shared__ __align__(16) unsigned short Bs[2][256][8];         //  8 KB

    int bid = blockIdx.x;
    int e   = bid & 7;
    int idx = bid >> 3;                  // 0..63
    int d0 = (idx >> 1) * 64;
    int ks = idx & 1;                    // K-half
    int k0 = ks * (FF / 2);
    float* OP = ks ? OPb : OPa;

    int Me = counts[e];
    if (Me == 0) return;
    int off = offsets[e];

    int t = threadIdx.x;
    int lane = t & 63;
    int w = t >> 6;
    int wm = w >> 1, wn = w & 1;
    int l15 = lane & 15, lg = lane >> 4;

    const float* w2e = w2 + (size_t)e * FF * DIM + d0;

    // B role: half frag-chunk (4 k-strided fp32) per thread per epoch
    int bcol = t & 63, blg = (t >> 6) & 3, bhalf = t >> 8;
    const float* bsrc = w2e + (size_t)(k0 + blg * 8 + bhalf * 4) * DIM + bcol;
    int bch = bcol + blg * 64;

    const int NST = (FF / 2) / BKE;      // 64 epochs per K-half

    for (int mb = 0; mb < Me; mb += BM) {
        __syncthreads();
        const unsigned short* asrc0;
        const unsigned short* asrc1;
        {
            int m0 = t >> 2, c0 = t & 3;
            int rl0 = mb + m0;
            asrc0 = Hbuf + (size_t)(off + ((rl0 < Me) ? rl0 : (Me - 1))) * FF
                         + k0 + (((c0 - (m0 >> 1)) & 3) << 3);
            int i1 = 512 + t;
            int m1 = i1 >> 2, c1 = i1 & 3;
            int rl1 = mb + m1;
            asrc1 = Hbuf + (size_t)(off + ((rl1 < Me) ? rl1 : (Me - 1))) * FF
                         + k0 + (((c1 - (m1 >> 1)) & 3) << 3);
        }

        f32x4 acc[3][2];
#pragma unroll
        for (int f = 0; f < 3; ++f)
#pragma unroll
            for (int nf = 0; nf < 2; ++nf) acc[f][nf] = (f32x4){0.f, 0.f, 0.f, 0.f};

        unsigned short* pRd = As;
        unsigned short* pMd = As + ASZ;
        unsigned short* pWr = As + 2 * ASZ;

        float bX[4], bY[4];

        async16(&pRd[(size_t)t * 8], asrc0);
        if (t < 256) async16(&pRd[(size_t)(512 + t) * 8], asrc1);
        async16(&pMd[(size_t)t * 8], asrc0 + BKE);
        if (t < 256) async16(&pMd[(size_t)(512 + t) * 8], asrc1 + BKE);
        SCHEDBAR;
#pragma unroll
        for (int j = 0; j < 4; ++j) bX[j] = bsrc[(size_t)j * DIM];
        {
            uint2 u_;
            u_.x = cvtpk(bX[0], bX[1]);
            u_.y = cvtpk(bX[2], bX[3]);
            *(uint2*)&Bs[0][bch][bhalf * 4] = u_;
        }
#pragma unroll
        for (int j = 0; j < 4; ++j) bY[j] = bsrc[(size_t)(BKE + j) * DIM];
        LGKMBAR;

        for (int s = 0; s < NST - 2; s += 2) {
            EP2(pRd, pWr, 0, 1, bY, bX, s,     1, 1);
            EP2(pMd, pRd, 1, 0, bX, bY, s + 1, 1, 1);
            unsigned short* tt = pRd; pRd = pWr; pWr = pMd; pMd = tt;
        }
        EP2(pRd, pWr, 0, 1, bY, bX, NST - 2, 0, 1);
        EP2(pMd, pRd, 1, 0, bX, bY, NST - 1, 0, 0);

#pragma unroll
        for (int f = 0; f < 3; ++f)
#pragma unroll
            for (int nf = 0; nf < 2; ++nf)
#pragma unroll
                for (int r = 0; r < 4; ++r) {
                    int rl = mb + wm * 48 + f * 16 + lg * 4 + r;
                    if (rl < Me) {
                        int grow = off + rl;
                        float g = row_gatew[grow];
                        OP[(size_t)grow * DIM + d0 + wn * 32 + nf * 16 + l15] =
                            acc[f][nf][r] * g;
                    }
                }
    }
}

// ---------------------------------------------------------------------------
// Kernel 5: out[token] = OPa[p0]+OPb[p0] + OPa[p1]+OPb[p1]
// ---------------------------------------------------------------------------
__global__ void combine(const float* __restrict__ OPa, const float* __restrict__ OPb,
                        const int* __restrict__ pair_row, float* __restrict__ out) {
    int idx = blockIdx.x * blockDim.x + threadIdx.x;
    int token = idx >> 9;
    int q = idx & 511;
    int r0 = pair_row[token * 2 + 0];
    int r1 = pair_row[token * 2 + 1];
    float4 a0 = *(const float4*)(OPa + (size_t)r0 * DIM + q * 4);
    float4 b0 = *(const float4*)(OPb + (size_t)r0 * DIM + q * 4);
    float4 a1 = *(const float4*)(OPa + (size_t)r1 * DIM + q * 4);
    float4 b1 = *(const float4*)(OPb + (size_t)r1 * DIM + q * 4);
    float4 o;
    o.x = (a0.x + b0.x) + (a1.x + b1.x);
    o.y = (a0.y + b0.y) + (a1.y + b1.y);
    o.z = (a0.z + b0.z) + (a1.z + b1.z);
    o.w = (a0.w + b0.w) + (a1.w + b1.w);
    *(float4*)(out + (size_t)token * DIM + q * 4) = o;
}

// ---------------------------------------------------------------------------
extern "C" void kernel_launch(void* const* d_in, const int* in_sizes, int n_in,
                              void* d_out, int out_size, void* d_ws, size_t ws_size,
                              hipStream_t stream) {
    const float* x  = (const float*)d_in[0];
    const float* gw = (const float*)d_in[1];
    const float* w1 = (const float*)d_in[2];
    const float* w3 = (const float*)d_in[3];
    const float* w2 = (const float*)d_in[4];
    float* out = (float*)d_out;

    char* ws = (char*)d_ws;
    unsigned short* Hbuf = (unsigned short*)ws;                 //  8 MB bf16 [1024][4096]
    float* OPa           = (float*)(ws + 8388608);              //  8 MB f32  [1024][2048]
    unsigned short* xbf  = (unsigned short*)(ws + 16777216);    //  2 MB bf16 [512][2048]
    float* OPb           = (float*)(ws + 20971520);             //  8 MB f32  [1024][2048]
    char* meta           = ws + 29360128;
    int*   tok_expert = (int*)(meta);
    float* tok_gatew  = (float*)(meta + 4096);
    int*   counts     = (int*)(meta + 8192);
    int*   offsets    = (int*)(meta + 8224);
    int*   row_token  = (int*)(meta + 8256);
    float* row_gatew  = (float*)(meta + 12352);
    int*   pair_row   = (int*)(meta + 16448);

    gate_topk<<<TOK, 64, 0, stream>>>(x, gw, xbf, tok_expert, tok_gatew);
    build_lists<<<1, 512, 0, stream>>>(tok_expert, tok_gatew, counts, offsets,
                                       row_token, row_gatew, pair_row);
    ffn1<<<NE * 32, 1024, 0, stream>>>(xbf, w1, w3, counts, offsets, row_token, Hbuf);
    ffn2<<<NE * 64, 512, 0, stream>>>(Hbuf, w2, counts, offsets, row_gatew, OPa, OPb);
    combine<<<1024, 256, 0, stream>>>(OPa, OPb, pair_row, out);
}